// Round 2
// baseline (1009.634 us; speedup 1.0000x reference)
//
#include <hip/hip_runtime.h>

// Problem geometry (mirrors reference constants)
constexpr int H = 200;
constexpr int W = 200;
constexpr int SDF_SIZE   = H * W;                 // 40000
constexpr int END_SDF    = SDF_SIZE;              // 40000
constexpr int END_GRAD   = END_SDF + 2 * SDF_SIZE; // 120000
constexpr int END_RES    = END_GRAD + 2;          // 120002
constexpr int END_ORIGIN = END_RES + 2;           // 120004
constexpr int IN_WIDTH   = END_ORIGIN + 2;        // 120006
constexpr float OOB_VALUE = -0.1f;

// One thread per batch row. Latency-bound: 3x float2 loads (params are
// 8B-aligned: row stride 120006 floats is even, END_GRAD/END_RES/END_ORIGIN
// are even) + 1 gathered scalar load + 1 store.
__global__ __launch_bounds__(256) void sdf_lookup_kernel(
    const float* __restrict__ in, float* __restrict__ out, int B) {
    int row = blockIdx.x * blockDim.x + threadIdx.x;
    if (row >= B) return;

    const float* rp = in + (size_t)row * IN_WIDTH;

    // res / origin / point: 3 contiguous float pairs starting at END_GRAD
    float2 res = *reinterpret_cast<const float2*>(rp + END_GRAD);
    float2 org = *reinterpret_cast<const float2*>(rp + END_RES);
    float2 pt  = *reinterpret_cast<const float2*>(rp + END_ORIGIN);

    // Exact IEEE division: the quotient feeds int truncation, a fast-rcp
    // ULP error at a cell boundary would flip the gathered index.
    float fx = pt.x / res.x + org.x;
    float fy = pt.y / res.y + org.y;

    int ix = (int)fx;   // trunc-toward-zero == astype(int32)
    int iy = (int)fy;

    bool oob = (ix < 0) | (ix >= W) | (iy < 0) | (iy >= H);

    int flat = ix * W + iy;
    int idx  = min(max(flat, 0), SDF_SIZE - 1);

    float v = rp[idx];  // gather from this row's SDF block
    out[row] = oob ? OOB_VALUE : v;
}

extern "C" void kernel_launch(void* const* d_in, const int* in_sizes, int n_in,
                              void* d_out, int out_size, void* d_ws, size_t ws_size,
                              hipStream_t stream) {
    const float* in = (const float*)d_in[0];
    float* out = (float*)d_out;
    int B = out_size;  // one output per row (2048)
    int block = 256;
    int grid = (B + block - 1) / block;
    sdf_lookup_kernel<<<grid, block, 0, stream>>>(in, out, B);
}